// Round 19
// baseline (48.553 us; speedup 1.0000x reference)
//
#include <hip/hip_runtime.h>

#define HSIZE 2048          // d-histogram buckets; packed lo16=pixel reps, hi16=points (n<32768)
#define CSH   6             // cell shift (64 px cells)
#define CSZ   64
#define NCLDS 2048          // LDS cell capacity (this family: 34x60 = 2040)
#define QLP   10176         // LDS point capacity
#define TPP   16            // threads per point
#define TPB   640           // 40 pts/block -> 250 blocks (one round over 256 CUs)

// ---------------- ONE kernel: per-block build + query + last-block finish ----------------
// Each block counting-sorts ALL n points into its own LDS (order nondeterministic per block,
// but all consumers are order-invariant) and answers its 40 points. dd[i] = (d<<1)|rep via
// agent-scope atomic store (write-through, single writer). Election: __syncthreads drains
// the block's stores (vmcnt(0) before s_barrier), ticket atomicAdd on done (memset to 0 by
// a 4B fill node each call); last ticket re-reads dd ONCE via agent-scope atomic LOADS
// (plain coherent loads, no RMW serialization), caches in LDS, then hist+bsearch+selection.
__global__ __launch_bounds__(TPB, 1) void bqf_k(
    const int* __restrict__ kp, const float* __restrict__ sc,
    const int* __restrict__ nret_, const int* __restrict__ rows_, const int* __restrict__ cols_,
    int n, int* __restrict__ done, int* __restrict__ dd, float* __restrict__ out) {
    __shared__ int2 lpp[QLP];                  // sorted points; finish reuses as ldd cache
    __shared__ unsigned short lsi[QLP];        // original index per sorted slot
    __shared__ int2 lcell[NCLDS + 1];          // {off, maxbits}; finish reuses as suf+lhist
    __shared__ int cnt[NCLDS];                 // count -> scatter cursor
    __shared__ int wsum[8];
    __shared__ int wsuf[8];
    __shared__ int wtK[10], wtN[10];
    __shared__ int fin_s, rsh;
    int t = threadIdx.x, lane = t & 63, w = t >> 6;
    int rows = rows_[0], cols = cols_[0];
    int NCX = (cols + CSZ - 1) >> CSH;
    int NCY = (rows + CSZ - 1) >> CSH;
    int NC = NCX * NCY;
    const int4* kp4 = (const int4*)kp;

    // scalar config (all-block uniform)
    int nret = nret_[0];
    int mx = rows > cols ? rows : cols;
    int nr1 = nret > 1 ? nret : 1;
    int dvs = (int)sqrt((double)n / (double)nr1);   // Python int() truncation
    if (dvs < 1) dvs = 1;
    int high = mx / dvs; if (high < 1) high = 1;
    // Adaptive RMAX (exact, r14 derivation): if the packing bound at the first probe's
    // radius r1 is below kmin, the first probe forces high=k1-1; no later probe exceeds r1.
    int kmin = (int)llround((double)nret * (1.0 - 0.1));
    int k1 = (1 + high) / 2;
    int r1 = k1 / 2;
    long long packb = (long long)((rows - 1) / (r1 + 1) + 1) *
                      (long long)((cols - 1) / (r1 + 1) + 1);
    int RMAX = (packb < (long long)kmin) ? r1 : (high / 2);

    int gt = blockIdx.x * TPB + t;
    int q = gt >> 4, sub = gt & 15;            // q = ORIGINAL point index
    bool act = q < n;

    // prefetch own point (independent of build passes)
    int pk = 0, sb = 0, y = 0, x = 0, cy = 0, cx = 0;
    if (act) {
        int4 k = kp4[q];
        y = k.z; x = k.w;
        pk = (y << 16) | x;
        sb = __float_as_int(sc[q]);            // scores > 0: bit order == value order
        cy = y >> CSH; cx = x >> CSH;
    }

    bool fits = (NC <= NCLDS) && (n <= QLP);   // block-uniform -> barriers legal inside
    if (fits) {
        // ---- per-block build ----
        for (int i = t; i < NCLDS; i += TPB) { cnt[i] = 0; lcell[i].y = 0; }
        if (t == 0) { lcell[NCLDS].y = 0; }
        __syncthreads();
        for (int i = t; i < n; i += TPB) {
            int4 k = kp4[i];
            int c = (k.z >> CSH) * NCX + (k.w >> CSH);
            atomicAdd(&cnt[c], 1);
            atomicMax(&lcell[c].y, __float_as_int(sc[i]));
        }
        __syncthreads();
        // exclusive scan over NCLDS=2048: first 512 threads, 4 cells each, shfl scans
        int s4 = 0, l0 = 0, l1 = 0, l2 = 0, l3 = 0, xv = 0;
        if (t < 512) {
            int b = t * 4;
            l0 = cnt[b]; l1 = cnt[b + 1]; l2 = cnt[b + 2]; l3 = cnt[b + 3];
            s4 = l0 + l1 + l2 + l3;
            xv = s4;
            for (int o = 1; o < 64; o <<= 1) { int v = __shfl_up(xv, o); if (lane >= o) xv += v; }
            if (lane == 63) wsum[w] = xv;
        }
        __syncthreads();
        if (w == 0) {
            int v = (lane < 8) ? wsum[lane] : 0;
            for (int o = 1; o < 8; o <<= 1) { int u = __shfl_up(v, o); if (lane >= o) v += u; }
            if (lane < 8) wsum[lane] = v;               // inclusive wave totals
        }
        __syncthreads();
        if (t < 512) {
            int b = t * 4;
            int ex = ((w == 0) ? 0 : wsum[w - 1]) + xv - s4;
            int o0 = ex, o1 = ex + l0, o2 = o1 + l1, o3 = o2 + l2;
            lcell[b].x = o0; lcell[b + 1].x = o1; lcell[b + 2].x = o2; lcell[b + 3].x = o3;
            cnt[b] = o0; cnt[b + 1] = o1; cnt[b + 2] = o2; cnt[b + 3] = o3;   // scatter cursor
        }
        if (t == 0) lcell[NCLDS].x = n;        // sentinel (covers NC == NCLDS)
        __syncthreads();
        for (int i = t; i < n; i += TPB) {
            int4 k = kp4[i];
            int c = (k.z >> CSH) * NCX + (k.w >> CSH);
            int pos = atomicAdd(&cnt[c], 1);   // within-cell order nondeterministic (OK)
            int2 v; v.x = (k.z << 16) | k.w; v.y = __float_as_int(sc[i]);
            lpp[pos] = v;
            lsi[pos] = (unsigned short)i;
        }
        __syncthreads();

        // ---- query ----
        if (act) {
            int c0 = cy * NCX + cx;
            int lo = lcell[c0].x, hi = lcell[c0 + 1].x;
            // own-cell scan: pixel-max + rep (no same-pixel point with smaller orig index)
            int pmax = sb, rep = 1;
            for (int j = lo + sub; j < hi; j += TPP) {
                int2 v = lpp[j];
                if (v.x == pk) {
                    if (v.y > pmax) pmax = v.y;
                    if ((int)lsi[j] < q) rep = 0;
                }
            }
            pmax = max(pmax, __shfl_xor(pmax, 1)); pmax = max(pmax, __shfl_xor(pmax, 2));
            pmax = max(pmax, __shfl_xor(pmax, 4)); pmax = max(pmax, __shfl_xor(pmax, 8));
            rep = min(rep, __shfl_xor(rep, 1)); rep = min(rep, __shfl_xor(rep, 2));
            rep = min(rep, __shfl_xor(rep, 4)); rep = min(rep, __shfl_xor(rep, 8));
            int pb = pmax;

            int d = RMAX + 1;                          // "no higher within RMAX" sentinel
            for (int j = lo + sub; j < hi; j += TPP) { // ring 0: own cell
                int2 v = lpp[j];
                if (v.y > pb) {
                    int dy = y - (v.x >> 16);    dy = dy < 0 ? -dy : dy;
                    int dx = x - (v.x & 0xFFFF); dx = dx < 0 ? -dx : dx;
                    int c = dy > dx ? dy : dx;
                    if (c < d) d = c;
                }
            }
            d = min(d, __shfl_xor(d, 1)); d = min(d, __shfl_xor(d, 2));
            d = min(d, __shfl_xor(d, 4)); d = min(d, __shfl_xor(d, 8));

            for (int R = 1;; ++R) {                    // expanding rings
                int LB = (R - 1) * CSZ + 1;            // min possible distance from ring-R cells
                if (LB >= d) break;                    // covers d == RMAX+1 cap too
                for (int e = sub; e < 8 * R; e += TPP) {
                    int a, b;
                    if (e < 2 * R + 1)      { a = -R; b = -R + e; }
                    else if (e < 4 * R + 2) { a =  R; b = -R + (e - (2 * R + 1)); }
                    else { int ss = e - (4 * R + 2); a = -R + 1 + (ss >> 1); b = (ss & 1) ? R : -R; }
                    int ccy = cy + a, ccx = cx + b;
                    if (ccy < 0 || ccy >= NCY || ccx < 0 || ccx >= NCX) continue;
                    int cc = ccy * NCX + ccx;
                    int2 cm = lcell[cc];               // one ds_read_b64: {off, max}
                    if (cm.y <= pb) continue;          // no strictly-greater score in this cell
                    int jhi = lcell[cc + 1].x;
                    for (int j = cm.x; j < jhi; ++j) {
                        int2 v = lpp[j];
                        if (v.y > pb) {
                            int dy = y - (v.x >> 16);    dy = dy < 0 ? -dy : dy;
                            int dx = x - (v.x & 0xFFFF); dx = dx < 0 ? -dx : dx;
                            int c = dy > dx ? dy : dx;
                            if (c < d) d = c;
                        }
                    }
                }
                d = min(d, __shfl_xor(d, 1)); d = min(d, __shfl_xor(d, 2));
                d = min(d, __shfl_xor(d, 4)); d = min(d, __shfl_xor(d, 8));
            }
            if (sub == 0)
                __hip_atomic_store(&dd[q], (d << 1) | rep,
                                   __ATOMIC_RELAXED, __HIP_MEMORY_SCOPE_AGENT);
        }
    } else {
        // correctness-only fallback: brute force over all n points (never hit in this family)
        if (act) {
            int pmax = sb, rep = 1;
            for (int j = sub; j < n; j += TPP) {
                int4 k = kp4[j];
                if (k.z == y && k.w == x) {
                    int sj = __float_as_int(sc[j]);
                    if (sj > pmax) pmax = sj;
                    if (j < q) rep = 0;
                }
            }
            pmax = max(pmax, __shfl_xor(pmax, 1)); pmax = max(pmax, __shfl_xor(pmax, 2));
            pmax = max(pmax, __shfl_xor(pmax, 4)); pmax = max(pmax, __shfl_xor(pmax, 8));
            rep = min(rep, __shfl_xor(rep, 1)); rep = min(rep, __shfl_xor(rep, 2));
            rep = min(rep, __shfl_xor(rep, 4)); rep = min(rep, __shfl_xor(rep, 8));
            int pb = pmax;
            int d = RMAX + 1;
            for (int j = sub; j < n; j += TPP) {
                int4 k = kp4[j];
                int sj = __float_as_int(sc[j]);
                if (sj > pb) {
                    int dy = y - k.z; dy = dy < 0 ? -dy : dy;
                    int dx = x - k.w; dx = dx < 0 ? -dx : dx;
                    int c = dy > dx ? dy : dx;
                    if (c < d) d = c;
                }
            }
            d = min(d, __shfl_xor(d, 1)); d = min(d, __shfl_xor(d, 2));
            d = min(d, __shfl_xor(d, 4)); d = min(d, __shfl_xor(d, 8));
            if (sub == 0)
                __hip_atomic_store(&dd[q], (d << 1) | rep,
                                   __ATOMIC_RELAXED, __HIP_MEMORY_SCOPE_AGENT);
        }
    }

    // ---- completion election (no fences; barrier drains this block's stores) ----
    __syncthreads();
    if (t == 0) {
        int tk = atomicAdd(done, 1);               // done memset to 0 before this dispatch
        fin_s = (tk == (int)gridDim.x - 1);
    }
    __syncthreads();
    if (!fin_s) return;

    // ---- finish phase (last block only; reuse LDS) ----
    int* suf   = (int*)lcell;                      // [HSIZE+1]
    int* lhist = ((int*)lcell) + HSIZE + 1;        // [HSIZE]  (4097 <= 4098 ints total)
    int* ldd   = (int*)lpp;                        // [n] if n <= QLP*2
    bool cacheDD = (n <= QLP * 2);

    for (int i = t; i < HSIZE; i += TPB) lhist[i] = 0;
    __syncthreads();
    for (int i = t; i < n; i += TPB) {
        int dv = __hip_atomic_load(&dd[i], __ATOMIC_RELAXED, __HIP_MEMORY_SCOPE_AGENT);
        if (cacheDD) ldd[i] = dv;
        int d2 = dv >> 1;
        int hb = d2 < HSIZE ? d2 : HSIZE - 1;
        atomicAdd(&lhist[hb], (dv & 1) ? 0x10001 : 0x10000);   // LDS atomics: cheap
    }
    __syncthreads();

    // packed suffix sums (512 threads x 4 buckets); no cross-carry (sums <= n < 32768)
    int s0 = 0, s1 = 0, s2 = 0, s3 = 0, xv2 = 0;
    if (t < 512) {
        int bb = t * 4;
        int b0 = lhist[bb], b1 = lhist[bb + 1], b2 = lhist[bb + 2], b3 = lhist[bb + 3];
        s3 = b3; s2 = b2 + s3; s1 = b1 + s2; s0 = b0 + s1;
        xv2 = s0;
        for (int o = 1; o < 64; o <<= 1) { int v = __shfl_down(xv2, o); if (lane + o < 64) xv2 += v; }
        if (lane == 0) wsuf[w] = xv2;
    }
    __syncthreads();
    if (w == 0) {
        int v = (lane < 8) ? wsuf[lane] : 0;
        for (int o = 1; o < 8; o <<= 1) { int u = __shfl_down(v, o); if (lane + o < 8) v += u; }
        if (lane < 8) wsuf[lane] = v;              // inclusive suffix of wave totals
    }
    __syncthreads();
    if (t < 512) {
        int S = xv2 + ((w < 7) ? wsuf[w + 1] : 0);
        int after = S - s0;
        int bb = t * 4;
        suf[bb] = s0 + after; suf[bb + 1] = s1 + after;
        suf[bb + 2] = s2 + after; suf[bb + 3] = s3 + after;
    }
    if (t == 0) suf[HSIZE] = 0;
    __syncthreads();

    if (t == 0) {
        int kmax = (int)llround((double)nret * (1.0 + 0.1));
        int low = 1, prev_k = -1, r_final = -1;
        int hh = high;
        bool found = false;
        while (true) {
            int k = (low + hh) / 2;
            if (k == prev_k || low > hh) break;
            int r = k / 2;                               // == k_odd // 2 for both parities
            int cnt2 = (r + 1 <= HSIZE) ? (suf[r + 1] & 0xFFFF) : 0;
            if (cnt2 >= kmin && cnt2 <= kmax) { r_final = r; found = true; break; }
            else if (cnt2 < kmin) hh = k - 1;
            else low = k + 1;
            prev_k = k;
        }
        if (!found) {
            int kfb = prev_k > 0 ? prev_k : 1;
            r_final = kfb / 2;
        }
        rsh = r_final;
    }
    __syncthreads();
    int r = rsh;
    int m = (r + 1 <= HSIZE) ? (suf[r + 1] >> 16) : 0;   // total kept POINTS (hi16)

    // ordered selection: kept ascending, pad with non-kept ascending, truncate at nret
    unsigned long long lanemask = (lane == 0) ? 0ull : (~0ull >> (64 - lane));
    int runK = 0, runN = 0;
    for (int bb2 = 0; bb2 < n; bb2 += TPB) {
        int i = bb2 + t;
        bool valid = i < n;
        int dv = 0;
        if (valid) {
            if (cacheDD) dv = ldd[i];
            else dv = __hip_atomic_load(&dd[i], __ATOMIC_RELAXED, __HIP_MEMORY_SCOPE_AGENT);
        }
        bool f  = valid && ((dv >> 1) > r);
        bool nf = valid && !f;
        unsigned long long mk = __ballot(f);
        unsigned long long mn = __ballot(nf);
        int pkc = __popcll(mk & lanemask);
        int pnc = __popcll(mn & lanemask);
        if (lane == 0) { wtK[w] = __popcll(mk); wtN[w] = __popcll(mn); }
        __syncthreads();
        int exK = runK + pkc, exN = runN + pnc;
        for (int u = 0; u < w; ++u) { exK += wtK[u]; exN += wtN[u]; }
        int ctK = 0, ctN = 0;
        for (int u = 0; u < 10; ++u) { ctK += wtK[u]; ctN += wtN[u]; }
        __syncthreads();
        if (valid) {
            int slot = -1;
            if (f) {
                if (exK < nret) slot = exK;
            } else if (nf && m < nret && (m + exN) < nret) {
                slot = m + exN;
            }
            if (slot >= 0) {
                out[slot * 4 + 0] = (float)kp[i * 4 + 0];
                out[slot * 4 + 1] = (float)kp[i * 4 + 1];
                out[slot * 4 + 2] = (float)kp[i * 4 + 2];
                out[slot * 4 + 3] = (float)kp[i * 4 + 3];
                out[nret * 4 + slot] = sc[i];
            }
        }
        runK += ctK;
        runN += ctN;
    }
}

extern "C" void kernel_launch(void* const* d_in, const int* in_sizes, int n_in,
                              void* d_out, int out_size, void* d_ws, size_t ws_size,
                              hipStream_t stream) {
    const int*   kp   = (const int*)d_in[0];
    const float* sc   = (const float*)d_in[1];
    const int*   nret = (const int*)d_in[2];
    const int*   rows = (const int*)d_in[3];
    const int*   cols = (const int*)d_in[4];
    int n = in_sizes[1];                       // number of points

    int* done  = (int*)d_ws;                   // 16 ints
    int* dd    = done + 16;                    // n ints
    float* out = (float*)d_out;

    hipMemsetAsync(done, 0, sizeof(int), stream);   // zero ticket counter every call
    int qblocks = (int)(((long long)n * TPP + TPB - 1) / TPB);   // 250 for n=10000
    bqf_k<<<qblocks, TPB, 0, stream>>>(kp, sc, nret, rows, cols, n, done, dd, out);
}

// Round 20
// 35.974 us; speedup vs baseline: 1.3497x; 1.3497x over previous
//
#include <hip/hip_runtime.h>

#define HSIZE 2048          // d-histogram buckets; packed lo16=pixel reps, hi16=points (n<32768)
#define CSH   6             // cell shift (64 px cells)
#define CSZ   64
#define NCLDS 2048          // LDS cell capacity (this family: 34x60 = 2040)
#define QLP   10176         // LDS point capacity
#define TPP   16            // threads per point
#define TPB   1024          // 64 pts/block -> 157 blocks (one round, 16 waves/CU)
#define NIT   10            // ceil(QLP / TPB) build iterations (register cache depth)

// ---------------- K1: per-block build + query ----------------
// Each block counting-sorts ALL n points into its own LDS (order nondeterministic per block,
// but all consumers are order-invariant: min over cell sets, max over pixel sets, rep by
// original index). Build pass 1 caches records in registers; pass 2 scatters from registers
// (one global read pass total). dd[i] = (d<<1)|rep, single writer -> deterministic.
__global__ __launch_bounds__(TPB, 1) void bq_k(
    const int* __restrict__ kp, const float* __restrict__ sc,
    const int* __restrict__ nret_, const int* __restrict__ rows_, const int* __restrict__ cols_,
    int n, int* __restrict__ dd) {
    __shared__ int2 lpp[QLP];                  // {(y<<16)|x, score_bits} counting-sorted
    __shared__ unsigned short lsi[QLP];        // original index per sorted slot
    __shared__ int2 lcell[NCLDS + 1];          // {off, maxbits}
    __shared__ int cnt[NCLDS];                 // count -> scatter cursor
    __shared__ int wsum[16];
    int t = threadIdx.x, lane = t & 63, w = t >> 6;
    int rows = rows_[0], cols = cols_[0];
    int NCX = (cols + CSZ - 1) >> CSH;
    int NCY = (rows + CSZ - 1) >> CSH;
    int NC = NCX * NCY;
    const int4* kp4 = (const int4*)kp;

    // scalar config (all-block uniform)
    int nret = nret_[0];
    int mx = rows > cols ? rows : cols;
    int nr1 = nret > 1 ? nret : 1;
    int dvs = (int)sqrt((double)n / (double)nr1);   // Python int() truncation
    if (dvs < 1) dvs = 1;
    int high = mx / dvs; if (high < 1) high = 1;
    // Adaptive RMAX (exact, r14 derivation): if the packing bound at the first probe's
    // radius r1 is below kmin, the first probe forces high=k1-1; no later probe exceeds r1.
    int kmin = (int)llround((double)nret * (1.0 - 0.1));
    int k1 = (1 + high) / 2;
    int r1 = k1 / 2;
    long long packb = (long long)((rows - 1) / (r1 + 1) + 1) *
                      (long long)((cols - 1) / (r1 + 1) + 1);
    int RMAX = (packb < (long long)kmin) ? r1 : (high / 2);

    int gt = blockIdx.x * TPB + t;
    int q = gt >> 4, sub = gt & 15;            // q = ORIGINAL point index
    bool act = q < n;

    // prefetch own point (independent of build passes)
    int pk = 0, sb = 0, y = 0, x = 0, cy = 0, cx = 0;
    if (act) {
        int4 k = kp4[q];
        y = k.z; x = k.w;
        pk = (y << 16) | x;
        sb = __float_as_int(sc[q]);            // scores > 0: bit order == value order
        cy = y >> CSH; cx = x >> CSH;
    }

    bool fits = (NC <= NCLDS) && (n <= QLP);   // block-uniform -> barriers legal inside
    if (fits) {
        // ---- per-block build, pass 1: count + cellmax, register-cache records ----
        for (int i = t; i < NCLDS; i += TPB) { cnt[i] = 0; lcell[i].y = 0; }
        if (t == 0) lcell[NCLDS].y = 0;
        __syncthreads();
        int2 rv[NIT]; int rc[NIT];
        #pragma unroll
        for (int k2 = 0; k2 < NIT; ++k2) {
            int i = t + k2 * TPB;
            if (i < n) {
                int4 k = kp4[i];
                int c = (k.z >> CSH) * NCX + (k.w >> CSH);
                int2 v; v.x = (k.z << 16) | k.w; v.y = __float_as_int(sc[i]);
                rv[k2] = v; rc[k2] = c;
                atomicAdd(&cnt[c], 1);
                atomicMax(&lcell[c].y, v.y);
            }
        }
        __syncthreads();
        // exclusive scan over NCLDS=2048: 2 cells/thread, shfl scans (2 barriers)
        int b2 = t * 2;
        int l0 = cnt[b2], l1 = cnt[b2 + 1];
        int s2 = l0 + l1;
        int xv = s2;
        for (int o = 1; o < 64; o <<= 1) { int v = __shfl_up(xv, o); if (lane >= o) xv += v; }
        if (lane == 63) wsum[w] = xv;
        __syncthreads();
        if (w == 0) {
            int v = (lane < 16) ? wsum[lane] : 0;
            for (int o = 1; o < 16; o <<= 1) { int u = __shfl_up(v, o); if (lane >= o) v += u; }
            if (lane < 16) wsum[lane] = v;               // inclusive wave totals
        }
        __syncthreads();
        {
            int ex = ((w == 0) ? 0 : wsum[w - 1]) + xv - s2;
            lcell[b2].x = ex; lcell[b2 + 1].x = ex + l0;
            cnt[b2] = ex;     cnt[b2 + 1] = ex + l0;     // scatter cursor
        }
        if (t == 0) lcell[NCLDS].x = n;        // sentinel (covers NC == NCLDS)
        __syncthreads();
        // ---- pass 2: scatter from registers (no global re-read) ----
        #pragma unroll
        for (int k2 = 0; k2 < NIT; ++k2) {
            int i = t + k2 * TPB;
            if (i < n) {
                int pos = atomicAdd(&cnt[rc[k2]], 1);    // within-cell order nondeterministic (OK)
                lpp[pos] = rv[k2];
                lsi[pos] = (unsigned short)i;
            }
        }
        __syncthreads();

        // ---- query ----
        if (act) {
            int c0 = cy * NCX + cx;
            int lo = lcell[c0].x, hi = lcell[c0 + 1].x;
            // own-cell scan: pixel-max + rep (no same-pixel point with smaller orig index)
            int pmax = sb, rep = 1;
            for (int j = lo + sub; j < hi; j += TPP) {
                int2 v = lpp[j];
                if (v.x == pk) {
                    if (v.y > pmax) pmax = v.y;
                    if ((int)lsi[j] < q) rep = 0;
                }
            }
            pmax = max(pmax, __shfl_xor(pmax, 1)); pmax = max(pmax, __shfl_xor(pmax, 2));
            pmax = max(pmax, __shfl_xor(pmax, 4)); pmax = max(pmax, __shfl_xor(pmax, 8));
            rep = min(rep, __shfl_xor(rep, 1)); rep = min(rep, __shfl_xor(rep, 2));
            rep = min(rep, __shfl_xor(rep, 4)); rep = min(rep, __shfl_xor(rep, 8));
            int pb = pmax;

            int d = RMAX + 1;                          // "no higher within RMAX" sentinel
            for (int j = lo + sub; j < hi; j += TPP) { // ring 0: own cell
                int2 v = lpp[j];
                if (v.y > pb) {
                    int dy = y - (v.x >> 16);    dy = dy < 0 ? -dy : dy;
                    int dx = x - (v.x & 0xFFFF); dx = dx < 0 ? -dx : dx;
                    int c = dy > dx ? dy : dx;
                    if (c < d) d = c;
                }
            }
            d = min(d, __shfl_xor(d, 1)); d = min(d, __shfl_xor(d, 2));
            d = min(d, __shfl_xor(d, 4)); d = min(d, __shfl_xor(d, 8));

            for (int R = 1;; ++R) {                    // expanding rings
                int LB = (R - 1) * CSZ + 1;            // min possible distance from ring-R cells
                if (LB >= d) break;                    // covers d == RMAX+1 cap too
                for (int e = sub; e < 8 * R; e += TPP) {
                    int a, b;
                    if (e < 2 * R + 1)      { a = -R; b = -R + e; }
                    else if (e < 4 * R + 2) { a =  R; b = -R + (e - (2 * R + 1)); }
                    else { int ss = e - (4 * R + 2); a = -R + 1 + (ss >> 1); b = (ss & 1) ? R : -R; }
                    int ccy = cy + a, ccx = cx + b;
                    if (ccy < 0 || ccy >= NCY || ccx < 0 || ccx >= NCX) continue;
                    int cc = ccy * NCX + ccx;
                    int2 cm = lcell[cc];               // one ds_read_b64: {off, max}
                    if (cm.y <= pb) continue;          // no strictly-greater score in this cell
                    int jhi = lcell[cc + 1].x;
                    for (int j = cm.x; j < jhi; ++j) {
                        int2 v = lpp[j];
                        if (v.y > pb) {
                            int dy = y - (v.x >> 16);    dy = dy < 0 ? -dy : dy;
                            int dx = x - (v.x & 0xFFFF); dx = dx < 0 ? -dx : dx;
                            int c = dy > dx ? dy : dx;
                            if (c < d) d = c;
                        }
                    }
                }
                d = min(d, __shfl_xor(d, 1)); d = min(d, __shfl_xor(d, 2));
                d = min(d, __shfl_xor(d, 4)); d = min(d, __shfl_xor(d, 8));
            }
            if (sub == 0) dd[q] = (d << 1) | rep;      // plain store, single writer
        }
    } else {
        // correctness-only fallback: brute force over all n points (never hit in this family)
        if (act) {
            int pmax = sb, rep = 1;
            for (int j = sub; j < n; j += TPP) {
                int4 k = kp4[j];
                if (k.z == y && k.w == x) {
                    int sj = __float_as_int(sc[j]);
                    if (sj > pmax) pmax = sj;
                    if (j < q) rep = 0;
                }
            }
            pmax = max(pmax, __shfl_xor(pmax, 1)); pmax = max(pmax, __shfl_xor(pmax, 2));
            pmax = max(pmax, __shfl_xor(pmax, 4)); pmax = max(pmax, __shfl_xor(pmax, 8));
            rep = min(rep, __shfl_xor(rep, 1)); rep = min(rep, __shfl_xor(rep, 2));
            rep = min(rep, __shfl_xor(rep, 4)); rep = min(rep, __shfl_xor(rep, 8));
            int pb = pmax;
            int d = RMAX + 1;
            for (int j = sub; j < n; j += TPP) {
                int4 k = kp4[j];
                int sj = __float_as_int(sc[j]);
                if (sj > pb) {
                    int dy = y - k.z; dy = dy < 0 ? -dy : dy;
                    int dx = x - k.w; dx = dx < 0 ? -dx : dx;
                    int c = dy > dx ? dy : dx;
                    if (c < d) d = c;
                }
            }
            d = min(d, __shfl_xor(d, 1)); d = min(d, __shfl_xor(d, 2));
            d = min(d, __shfl_xor(d, 4)); d = min(d, __shfl_xor(d, 8));
            if (sub == 0) dd[q] = (d << 1) | rep;
        }
    }
}

// ---------------- K2: LDS histogram + binary-search replica + ordered select ----------------
__global__ __launch_bounds__(1024) void finish_k(
    const int* __restrict__ kp, const float* __restrict__ sc,
    const int* __restrict__ dd,
    const int* __restrict__ nret_, const int* __restrict__ rows_, const int* __restrict__ cols_,
    int n, float* __restrict__ out) {
    __shared__ int lhist[HSIZE];
    __shared__ int suf[HSIZE + 1];
    __shared__ int wsuf[16];
    __shared__ int wtK[16], wtN[16];
    __shared__ int rsh;
    int t = threadIdx.x, lane = t & 63, w = t >> 6;

    // build packed histogram from dd in LDS (lo16 = pixel reps, hi16 = points)
    lhist[t] = 0; lhist[t + 1024] = 0;
    __syncthreads();
    for (int i = t; i < n; i += 1024) {
        int dv = dd[i];
        int d = dv >> 1;
        int hb = d < HSIZE ? d : HSIZE - 1;
        atomicAdd(&lhist[hb], (dv & 1) ? 0x10001 : 0x10000);
    }
    __syncthreads();

    // packed suffix sums via shfl; no cross-carry: each component sum <= n < 32768
    int b0 = lhist[2 * t], b1 = lhist[2 * t + 1];
    int s = b0 + b1;
    int x = s;
    for (int o = 1; o < 64; o <<= 1) { int v = __shfl_down(x, o); if (lane + o < 64) x += v; }
    if (lane == 0) wsuf[w] = x;
    __syncthreads();
    if (w == 0) {
        int v = (lane < 16) ? wsuf[lane] : 0;
        for (int o = 1; o < 16; o <<= 1) { int u = __shfl_down(v, o); if (lane + o < 16) v += u; }
        if (lane < 16) wsuf[lane] = v;             // inclusive suffix of wave totals
    }
    __syncthreads();
    int S = x + ((w < 15) ? wsuf[w + 1] : 0);
    suf[2 * t] = S;
    suf[2 * t + 1] = S - b0;
    if (t == 0) suf[HSIZE] = 0;
    __syncthreads();

    if (t == 0) {
        int nret = nret_[0];
        int rows = rows_[0], cols = cols_[0];
        int kmin = (int)llround((double)nret * (1.0 - 0.1));
        int kmax = (int)llround((double)nret * (1.0 + 0.1));
        int mx = rows > cols ? rows : cols;
        int nr1 = nret > 1 ? nret : 1;
        int dvs = (int)sqrt((double)n / (double)nr1);
        if (dvs < 1) dvs = 1;
        int high = mx / dvs; if (high < 1) high = 1;
        int low = 1, prev_k = -1, r_final = -1;
        bool found = false;
        while (true) {
            int k = (low + high) / 2;
            if (k == prev_k || low > high) break;
            int r = k / 2;                               // == k_odd // 2 for both parities
            int cnt = (r + 1 <= HSIZE) ? (suf[r + 1] & 0xFFFF) : 0;
            if (cnt >= kmin && cnt <= kmax) { r_final = r; found = true; break; }
            else if (cnt < kmin) high = k - 1;
            else low = k + 1;
            prev_k = k;
        }
        if (!found) {
            int kfb = prev_k > 0 ? prev_k : 1;
            r_final = kfb / 2;
        }
        rsh = r_final;
    }
    __syncthreads();
    int r = rsh;
    int nret = nret_[0];
    int m = (r + 1 <= HSIZE) ? (suf[r + 1] >> 16) : 0;   // total kept POINTS (hi16)

    // ordered selection: kept ascending, pad with non-kept ascending, truncate at nret
    unsigned long long lanemask = (lane == 0) ? 0ull : (~0ull >> (64 - lane));
    int runK = 0, runN = 0;
    for (int bb = 0; bb < n; bb += 1024) {
        int i = bb + t;
        bool valid = i < n;
        bool f  = valid && ((dd[i] >> 1) > r);
        bool nf = valid && !f;
        unsigned long long mk = __ballot(f);
        unsigned long long mn = __ballot(nf);
        int pk = __popcll(mk & lanemask);
        int pn = __popcll(mn & lanemask);
        if (lane == 0) { wtK[w] = __popcll(mk); wtN[w] = __popcll(mn); }
        __syncthreads();
        int exK = runK + pk, exN = runN + pn;
        for (int u = 0; u < w; ++u) { exK += wtK[u]; exN += wtN[u]; }
        int ctK = 0, ctN = 0;
        for (int u = 0; u < 16; ++u) { ctK += wtK[u]; ctN += wtN[u]; }
        __syncthreads();
        if (valid) {
            int slot = -1;
            if (f) {
                if (exK < nret) slot = exK;
            } else if (nf && m < nret && (m + exN) < nret) {
                slot = m + exN;
            }
            if (slot >= 0) {
                out[slot * 4 + 0] = (float)kp[i * 4 + 0];
                out[slot * 4 + 1] = (float)kp[i * 4 + 1];
                out[slot * 4 + 2] = (float)kp[i * 4 + 2];
                out[slot * 4 + 3] = (float)kp[i * 4 + 3];
                out[nret * 4 + slot] = sc[i];
            }
        }
        runK += ctK;
        runN += ctN;
    }
}

extern "C" void kernel_launch(void* const* d_in, const int* in_sizes, int n_in,
                              void* d_out, int out_size, void* d_ws, size_t ws_size,
                              hipStream_t stream) {
    const int*   kp   = (const int*)d_in[0];
    const float* sc   = (const float*)d_in[1];
    const int*   nret = (const int*)d_in[2];
    const int*   rows = (const int*)d_in[3];
    const int*   cols = (const int*)d_in[4];
    int n = in_sizes[1];                       // number of points

    int* dd    = (int*)d_ws;                   // n ints
    float* out = (float*)d_out;

    int qblocks = (int)(((long long)n * TPP + TPB - 1) / TPB);   // 157 for n=10000
    bq_k<<<qblocks, TPB, 0, stream>>>(kp, sc, nret, rows, cols, n, dd);
    finish_k<<<1, 1024, 0, stream>>>(kp, sc, dd, nret, rows, cols, n, out);
}

// Round 21
// 34.836 us; speedup vs baseline: 1.3938x; 1.0327x over previous
//
#include <hip/hip_runtime.h>

#define HSIZE 2048          // d-histogram buckets; packed lo16=pixel reps, hi16=points (n<32768)
#define CSH   6             // cell shift (64 px cells)
#define CSZ   64
#define NCLDS 2048          // LDS cell capacity (this family: 34x60 = 2040)
#define QLP   10176         // LDS point capacity
#define TPP   16            // threads per point
#define TPB   1024          // 64 pts/block -> 157 blocks (one round, 16 waves/CU)
#define NIT   10            // ceil(QLP / TPB) build iterations (register cache depth)

// ---------------- K1: per-block build + query ----------------
// Each block counting-sorts ALL n points into its own LDS (order nondeterministic per block,
// but all consumers are order-invariant). Build pass 1 register-caches records; pass 2
// scatters from registers. Query: merged own-cell scan (fast path pb==sb) + box-LB cell
// prune. dd[i] = (d<<1)|rep, single writer -> deterministic.
__global__ __launch_bounds__(TPB, 1) void bq_k(
    const int* __restrict__ kp, const float* __restrict__ sc,
    const int* __restrict__ nret_, const int* __restrict__ rows_, const int* __restrict__ cols_,
    int n, int* __restrict__ dd) {
    __shared__ int2 lpp[QLP];                  // {(y<<16)|x, score_bits} counting-sorted
    __shared__ unsigned short lsi[QLP];        // original index per sorted slot
    __shared__ int2 lcell[NCLDS + 1];          // {off, maxbits}
    __shared__ int cnt[NCLDS];                 // count -> scatter cursor
    __shared__ int wsum[16];
    int t = threadIdx.x, lane = t & 63, w = t >> 6;
    int rows = rows_[0], cols = cols_[0];
    int NCX = (cols + CSZ - 1) >> CSH;
    int NCY = (rows + CSZ - 1) >> CSH;
    int NC = NCX * NCY;
    const int4* kp4 = (const int4*)kp;

    // scalar config (all-block uniform)
    int nret = nret_[0];
    int mx = rows > cols ? rows : cols;
    int nr1 = nret > 1 ? nret : 1;
    int dvs = (int)sqrt((double)n / (double)nr1);   // Python int() truncation
    if (dvs < 1) dvs = 1;
    int high = mx / dvs; if (high < 1) high = 1;
    // Adaptive RMAX (exact, r14 derivation): if the packing bound at the first probe's
    // radius r1 is below kmin, the first probe forces high=k1-1; no later probe exceeds r1.
    int kmin = (int)llround((double)nret * (1.0 - 0.1));
    int k1 = (1 + high) / 2;
    int r1 = k1 / 2;
    long long packb = (long long)((rows - 1) / (r1 + 1) + 1) *
                      (long long)((cols - 1) / (r1 + 1) + 1);
    int RMAX = (packb < (long long)kmin) ? r1 : (high / 2);

    int gt = blockIdx.x * TPB + t;
    int q = gt >> 4, sub = gt & 15;            // q = ORIGINAL point index
    bool act = q < n;

    // prefetch own point (independent of build passes)
    int pk = 0, sb = 0, y = 0, x = 0, cy = 0, cx = 0;
    if (act) {
        int4 k = kp4[q];
        y = k.z; x = k.w;
        pk = (y << 16) | x;
        sb = __float_as_int(sc[q]);            // scores > 0: bit order == value order
        cy = y >> CSH; cx = x >> CSH;
    }

    bool fits = (NC <= NCLDS) && (n <= QLP);   // block-uniform -> barriers legal inside
    if (fits) {
        // ---- per-block build, pass 1: count + cellmax, register-cache records ----
        for (int i = t; i < NCLDS; i += TPB) { cnt[i] = 0; lcell[i].y = 0; }
        if (t == 0) lcell[NCLDS].y = 0;
        __syncthreads();
        int2 rv[NIT]; int rc[NIT];
        #pragma unroll
        for (int k2 = 0; k2 < NIT; ++k2) {
            int i = t + k2 * TPB;
            if (i < n) {
                int4 k = kp4[i];
                int c = (k.z >> CSH) * NCX + (k.w >> CSH);
                int2 v; v.x = (k.z << 16) | k.w; v.y = __float_as_int(sc[i]);
                rv[k2] = v; rc[k2] = c;
                atomicAdd(&cnt[c], 1);
                atomicMax(&lcell[c].y, v.y);
            }
        }
        __syncthreads();
        // exclusive scan over NCLDS=2048: 2 cells/thread, shfl scans (2 barriers)
        int b2 = t * 2;
        int l0 = cnt[b2], l1 = cnt[b2 + 1];
        int s2 = l0 + l1;
        int xv = s2;
        for (int o = 1; o < 64; o <<= 1) { int v = __shfl_up(xv, o); if (lane >= o) xv += v; }
        if (lane == 63) wsum[w] = xv;
        __syncthreads();
        if (w == 0) {
            int v = (lane < 16) ? wsum[lane] : 0;
            for (int o = 1; o < 16; o <<= 1) { int u = __shfl_up(v, o); if (lane >= o) v += u; }
            if (lane < 16) wsum[lane] = v;               // inclusive wave totals
        }
        __syncthreads();
        {
            int ex = ((w == 0) ? 0 : wsum[w - 1]) + xv - s2;
            lcell[b2].x = ex; lcell[b2 + 1].x = ex + l0;
            cnt[b2] = ex;     cnt[b2 + 1] = ex + l0;     // scatter cursor
        }
        if (t == 0) lcell[NCLDS].x = n;        // sentinel (covers NC == NCLDS)
        __syncthreads();
        // ---- pass 2: scatter from registers (no global re-read) ----
        #pragma unroll
        for (int k2 = 0; k2 < NIT; ++k2) {
            int i = t + k2 * TPB;
            if (i < n) {
                int pos = atomicAdd(&cnt[rc[k2]], 1);    // within-cell order nondeterministic (OK)
                lpp[pos] = rv[k2];
                lsi[pos] = (unsigned short)i;
            }
        }
        __syncthreads();

        // ---- query ----
        if (act) {
            int c0 = cy * NCX + cx;
            int lo = lcell[c0].x, hi = lcell[c0 + 1].x;
            // MERGED own-cell scan: pixel-max + rep + provisional ring-0 dist (filter > sb)
            int pmax = sb, rep = 1;
            int d = RMAX + 1;                          // "no higher within RMAX" sentinel
            for (int j = lo + sub; j < hi; j += TPP) {
                int2 v = lpp[j];
                if (v.x == pk) {
                    if (v.y > pmax) pmax = v.y;
                    if ((int)lsi[j] < q) rep = 0;
                } else if (v.y > sb) {
                    int dy = y - (v.x >> 16);    dy = dy < 0 ? -dy : dy;
                    int dx = x - (v.x & 0xFFFF); dx = dx < 0 ? -dx : dx;
                    int c = dy > dx ? dy : dx;
                    if (c < d) d = c;
                }
            }
            pmax = max(pmax, __shfl_xor(pmax, 1)); pmax = max(pmax, __shfl_xor(pmax, 2));
            pmax = max(pmax, __shfl_xor(pmax, 4)); pmax = max(pmax, __shfl_xor(pmax, 8));
            rep = min(rep, __shfl_xor(rep, 1)); rep = min(rep, __shfl_xor(rep, 2));
            rep = min(rep, __shfl_xor(rep, 4)); rep = min(rep, __shfl_xor(rep, 8));
            d = min(d, __shfl_xor(d, 1)); d = min(d, __shfl_xor(d, 2));
            d = min(d, __shfl_xor(d, 4)); d = min(d, __shfl_xor(d, 8));
            int pb = pmax;
            if (pb != sb) {
                // rare (duplicate pixel with higher score): redo ring 0 with exact filter
                d = RMAX + 1;
                for (int j = lo + sub; j < hi; j += TPP) {
                    int2 v = lpp[j];
                    if (v.x != pk && v.y > pb) {
                        int dy = y - (v.x >> 16);    dy = dy < 0 ? -dy : dy;
                        int dx = x - (v.x & 0xFFFF); dx = dx < 0 ? -dx : dx;
                        int c = dy > dx ? dy : dx;
                        if (c < d) d = c;
                    }
                }
                d = min(d, __shfl_xor(d, 1)); d = min(d, __shfl_xor(d, 2));
                d = min(d, __shfl_xor(d, 4)); d = min(d, __shfl_xor(d, 8));
            }

            for (int R = 1;; ++R) {                    // expanding rings
                int LB = (R - 1) * CSZ + 1;            // min possible distance from ring-R cells
                if (LB >= d) break;                    // covers d == RMAX+1 cap too
                for (int e = sub; e < 8 * R; e += TPP) {
                    int a, b;
                    if (e < 2 * R + 1)      { a = -R; b = -R + e; }
                    else if (e < 4 * R + 2) { a =  R; b = -R + (e - (2 * R + 1)); }
                    else { int ss = e - (4 * R + 2); a = -R + 1 + (ss >> 1); b = (ss & 1) ? R : -R; }
                    int ccy = cy + a, ccx = cx + b;
                    if (ccy < 0 || ccy >= NCY || ccx < 0 || ccx >= NCX) continue;
                    // geometric box-LB (pure VALU): every point in cell is >= clb away
                    int cy0 = ccy << CSH, cx0 = ccx << CSH;
                    int dyb = (y < cy0) ? (cy0 - y) : (y - (cy0 + CSZ - 1));
                    if (dyb < 0) dyb = 0;
                    int dxb = (x < cx0) ? (cx0 - x) : (x - (cx0 + CSZ - 1));
                    if (dxb < 0) dxb = 0;
                    int clb = dyb > dxb ? dyb : dxb;
                    if (clb >= d) continue;            // cannot improve this lane's d
                    int cc = ccy * NCX + ccx;
                    int2 cm = lcell[cc];               // one ds_read_b64: {off, max}
                    if (cm.y <= pb) continue;          // no strictly-greater score in this cell
                    int jhi = lcell[cc + 1].x;
                    for (int j = cm.x; j < jhi; ++j) {
                        int2 v = lpp[j];
                        if (v.y > pb) {
                            int dy = y - (v.x >> 16);    dy = dy < 0 ? -dy : dy;
                            int dx = x - (v.x & 0xFFFF); dx = dx < 0 ? -dx : dx;
                            int c = dy > dx ? dy : dx;
                            if (c < d) d = c;
                        }
                    }
                }
                d = min(d, __shfl_xor(d, 1)); d = min(d, __shfl_xor(d, 2));
                d = min(d, __shfl_xor(d, 4)); d = min(d, __shfl_xor(d, 8));
            }
            if (sub == 0) dd[q] = (d << 1) | rep;      // plain store, single writer
        }
    } else {
        // correctness-only fallback: brute force over all n points (never hit in this family)
        if (act) {
            int pmax = sb, rep = 1;
            for (int j = sub; j < n; j += TPP) {
                int4 k = kp4[j];
                if (k.z == y && k.w == x) {
                    int sj = __float_as_int(sc[j]);
                    if (sj > pmax) pmax = sj;
                    if (j < q) rep = 0;
                }
            }
            pmax = max(pmax, __shfl_xor(pmax, 1)); pmax = max(pmax, __shfl_xor(pmax, 2));
            pmax = max(pmax, __shfl_xor(pmax, 4)); pmax = max(pmax, __shfl_xor(pmax, 8));
            rep = min(rep, __shfl_xor(rep, 1)); rep = min(rep, __shfl_xor(rep, 2));
            rep = min(rep, __shfl_xor(rep, 4)); rep = min(rep, __shfl_xor(rep, 8));
            int pb = pmax;
            int d = RMAX + 1;
            for (int j = sub; j < n; j += TPP) {
                int4 k = kp4[j];
                int sj = __float_as_int(sc[j]);
                if (sj > pb) {
                    int dy = y - k.z; dy = dy < 0 ? -dy : dy;
                    int dx = x - k.w; dx = dx < 0 ? -dx : dx;
                    int c = dy > dx ? dy : dx;
                    if (c < d) d = c;
                }
            }
            d = min(d, __shfl_xor(d, 1)); d = min(d, __shfl_xor(d, 2));
            d = min(d, __shfl_xor(d, 4)); d = min(d, __shfl_xor(d, 8));
            if (sub == 0) dd[q] = (d << 1) | rep;
        }
    }
}

// ---------------- K2: LDS histogram + binary-search replica + ordered select ----------------
__global__ __launch_bounds__(1024) void finish_k(
    const int* __restrict__ kp, const float* __restrict__ sc,
    const int* __restrict__ dd,
    const int* __restrict__ nret_, const int* __restrict__ rows_, const int* __restrict__ cols_,
    int n, float* __restrict__ out) {
    __shared__ int lhist[HSIZE];
    __shared__ int suf[HSIZE + 1];
    __shared__ int wsuf[16];
    __shared__ int wtK[16], wtN[16];
    __shared__ int rsh;
    int t = threadIdx.x, lane = t & 63, w = t >> 6;

    // build packed histogram from dd in LDS (lo16 = pixel reps, hi16 = points)
    lhist[t] = 0; lhist[t + 1024] = 0;
    __syncthreads();
    for (int i = t; i < n; i += 1024) {
        int dv = dd[i];
        int d = dv >> 1;
        int hb = d < HSIZE ? d : HSIZE - 1;
        atomicAdd(&lhist[hb], (dv & 1) ? 0x10001 : 0x10000);
    }
    __syncthreads();

    // packed suffix sums via shfl; no cross-carry: each component sum <= n < 32768
    int b0 = lhist[2 * t], b1 = lhist[2 * t + 1];
    int s = b0 + b1;
    int x = s;
    for (int o = 1; o < 64; o <<= 1) { int v = __shfl_down(x, o); if (lane + o < 64) x += v; }
    if (lane == 0) wsuf[w] = x;
    __syncthreads();
    if (w == 0) {
        int v = (lane < 16) ? wsuf[lane] : 0;
        for (int o = 1; o < 16; o <<= 1) { int u = __shfl_down(v, o); if (lane + o < 16) v += u; }
        if (lane < 16) wsuf[lane] = v;             // inclusive suffix of wave totals
    }
    __syncthreads();
    int S = x + ((w < 15) ? wsuf[w + 1] : 0);
    suf[2 * t] = S;
    suf[2 * t + 1] = S - b0;
    if (t == 0) suf[HSIZE] = 0;
    __syncthreads();

    if (t == 0) {
        int nret = nret_[0];
        int rows = rows_[0], cols = cols_[0];
        int kmin = (int)llround((double)nret * (1.0 - 0.1));
        int kmax = (int)llround((double)nret * (1.0 + 0.1));
        int mx = rows > cols ? rows : cols;
        int nr1 = nret > 1 ? nret : 1;
        int dvs = (int)sqrt((double)n / (double)nr1);
        if (dvs < 1) dvs = 1;
        int high = mx / dvs; if (high < 1) high = 1;
        int low = 1, prev_k = -1, r_final = -1;
        bool found = false;
        while (true) {
            int k = (low + high) / 2;
            if (k == prev_k || low > high) break;
            int r = k / 2;                               // == k_odd // 2 for both parities
            int cnt = (r + 1 <= HSIZE) ? (suf[r + 1] & 0xFFFF) : 0;
            if (cnt >= kmin && cnt <= kmax) { r_final = r; found = true; break; }
            else if (cnt < kmin) high = k - 1;
            else low = k + 1;
            prev_k = k;
        }
        if (!found) {
            int kfb = prev_k > 0 ? prev_k : 1;
            r_final = kfb / 2;
        }
        rsh = r_final;
    }
    __syncthreads();
    int r = rsh;
    int nret = nret_[0];
    int m = (r + 1 <= HSIZE) ? (suf[r + 1] >> 16) : 0;   // total kept POINTS (hi16)

    // ordered selection: kept ascending, pad with non-kept ascending, truncate at nret
    unsigned long long lanemask = (lane == 0) ? 0ull : (~0ull >> (64 - lane));
    int runK = 0, runN = 0;
    for (int bb = 0; bb < n; bb += 1024) {
        int i = bb + t;
        bool valid = i < n;
        bool f  = valid && ((dd[i] >> 1) > r);
        bool nf = valid && !f;
        unsigned long long mk = __ballot(f);
        unsigned long long mn = __ballot(nf);
        int pk = __popcll(mk & lanemask);
        int pn = __popcll(mn & lanemask);
        if (lane == 0) { wtK[w] = __popcll(mk); wtN[w] = __popcll(mn); }
        __syncthreads();
        int exK = runK + pk, exN = runN + pn;
        for (int u = 0; u < w; ++u) { exK += wtK[u]; exN += wtN[u]; }
        int ctK = 0, ctN = 0;
        for (int u = 0; u < 16; ++u) { ctK += wtK[u]; ctN += wtN[u]; }
        __syncthreads();
        if (valid) {
            int slot = -1;
            if (f) {
                if (exK < nret) slot = exK;
            } else if (nf && m < nret && (m + exN) < nret) {
                slot = m + exN;
            }
            if (slot >= 0) {
                out[slot * 4 + 0] = (float)kp[i * 4 + 0];
                out[slot * 4 + 1] = (float)kp[i * 4 + 1];
                out[slot * 4 + 2] = (float)kp[i * 4 + 2];
                out[slot * 4 + 3] = (float)kp[i * 4 + 3];
                out[nret * 4 + slot] = sc[i];
            }
        }
        runK += ctK;
        runN += ctN;
    }
}

extern "C" void kernel_launch(void* const* d_in, const int* in_sizes, int n_in,
                              void* d_out, int out_size, void* d_ws, size_t ws_size,
                              hipStream_t stream) {
    const int*   kp   = (const int*)d_in[0];
    const float* sc   = (const float*)d_in[1];
    const int*   nret = (const int*)d_in[2];
    const int*   rows = (const int*)d_in[3];
    const int*   cols = (const int*)d_in[4];
    int n = in_sizes[1];                       // number of points

    int* dd    = (int*)d_ws;                   // n ints
    float* out = (float*)d_out;

    int qblocks = (int)(((long long)n * TPP + TPB - 1) / TPB);   // 157 for n=10000
    bq_k<<<qblocks, TPB, 0, stream>>>(kp, sc, nret, rows, cols, n, dd);
    finish_k<<<1, 1024, 0, stream>>>(kp, sc, dd, nret, rows, cols, n, out);
}